// Round 10
// baseline (263.233 us; speedup 1.0000x reference)
//
#include <hip/hip_runtime.h>
#include <math.h>

// BertFlashSelfAttention (varlen, H=16, D=64)
// Phase 0: fp32 -> f16 convert (hidden, Wqkv)
// Phase 1: QKV GEMM, BK=64, XOR-swizzled LDS (validated r9)
// Phase 2: MFMA flash attention: swapped-QK^T softmax (r8), K read direct
//          from L2 (no K LDS), defer-max THR=8 (T13), issue-early V (T14).

#define HD 64

typedef _Float16 half8 __attribute__((ext_vector_type(8)));
typedef _Float16 half4v __attribute__((ext_vector_type(4)));
typedef float f32x4 __attribute__((ext_vector_type(4)));

#define GLP(p) ((__attribute__((address_space(1))) void*)(p))
#define LDSP(p) ((__attribute__((address_space(3))) void*)(p))

// ---------------------------------------------------------------------------
// fp32 -> f16 conversion (grid-stride, float4 in / half4 out)
// ---------------------------------------------------------------------------
__global__ __launch_bounds__(256)
void cvt_kernel(const float* __restrict__ A, const float* __restrict__ W,
                _Float16* __restrict__ Ah, _Float16* __restrict__ Wh,
                int nA4, int nW4)
{
    int total = nA4 + nW4;
    for (int i = blockIdx.x * blockDim.x + threadIdx.x; i < total;
         i += gridDim.x * blockDim.x) {
        const float* src; _Float16* dst; int j;
        if (i < nA4) { src = A; dst = Ah; j = i; }
        else         { src = W; dst = Wh; j = i - nA4; }
        float4 v = *(const float4*)(src + (size_t)j * 4);
        half4v h;
        h.x = (_Float16)v.x; h.y = (_Float16)v.y;
        h.z = (_Float16)v.z; h.w = (_Float16)v.w;
        *(half4v*)(dst + (size_t)j * 4) = h;
    }
}

// ---------------------------------------------------------------------------
// QKV GEMM (unchanged, validated r9): BK=64, XOR-swizzled LDS, f16 MFMA.
// ---------------------------------------------------------------------------
__global__ __launch_bounds__(256)
void qkv_gemm_kernel(const _Float16* __restrict__ Ah, const _Float16* __restrict__ Wh,
                     const float* __restrict__ bias,
                     _Float16* __restrict__ Qo, _Float16* __restrict__ Ko,
                     _Float16* __restrict__ Vo,
                     int Kd, int dim)
{
    const int bm = blockIdx.x, bn = blockIdx.y;
    const int t = threadIdx.x;
    const int wid = t >> 6, lane = t & 63;
    const int wr = wid >> 1, wc = wid & 1;
    const int fr = lane & 15, fq = lane >> 4;

    __shared__ _Float16 As[128 * 64];   // 16 KB, swizzled 128B rows
    __shared__ _Float16 Bs[128 * 64];

    const int m0 = bm * 128, n0 = bn * 128;

    f32x4 acc[4][4];
#pragma unroll
    for (int m = 0; m < 4; ++m)
#pragma unroll
        for (int n = 0; n < 4; ++n) acc[m][n] = (f32x4)0.f;

    float biasv[4];
#pragma unroll
    for (int n = 0; n < 4; ++n)
        biasv[n] = bias[n0 + wc * 64 + n * 16 + fr];

    int srow[4], slb[4];
#pragma unroll
    for (int i = 0; i < 4; ++i) {
        int c = t + 256 * i;
        srow[i] = c >> 3;
        slb[i]  = ((c & 7) << 4) ^ ((srow[i] & 7) << 4);
    }

    for (int k0 = 0; k0 < Kd; k0 += 64) {
        __syncthreads();
        {
            const char* Ab = (const char*)Ah + ((size_t)m0 * Kd + k0) * 2;
            const char* Bb = (const char*)Wh + ((size_t)n0 * Kd + k0) * 2;
#pragma unroll
            for (int i = 0; i < 4; ++i) {
                int phys = (t + 256 * i) * 16;
                __builtin_amdgcn_global_load_lds(GLP(Ab + (size_t)srow[i] * Kd * 2 + slb[i]),
                                                 LDSP((char*)As + phys), 16, 0, 0);
                __builtin_amdgcn_global_load_lds(GLP(Bb + (size_t)srow[i] * Kd * 2 + slb[i]),
                                                 LDSP((char*)Bs + phys), 16, 0, 0);
            }
        }
        __syncthreads();

#pragma unroll
        for (int kc = 0; kc < 2; ++kc) {
            half8 a[4], b[4];
#pragma unroll
            for (int m = 0; m < 4; ++m) {
                int row = wr * 64 + m * 16 + fr;
                a[m] = *(const half8*)((const char*)As + row * 128 +
                        ((kc * 64 + fq * 16) ^ ((fr & 7) << 4)));
            }
#pragma unroll
            for (int n = 0; n < 4; ++n) {
                int row = wc * 64 + n * 16 + fr;
                b[n] = *(const half8*)((const char*)Bs + row * 128 +
                        ((kc * 64 + fq * 16) ^ ((fr & 7) << 4)));
            }
#pragma unroll
            for (int m = 0; m < 4; ++m)
#pragma unroll
                for (int n = 0; n < 4; ++n)
                    acc[m][n] = __builtin_amdgcn_mfma_f32_16x16x32_f16(a[m], b[n], acc[m][n], 0, 0, 0);
        }
    }

    const int which = n0 / dim;
    const int offb  = n0 - which * dim;
    _Float16* dst = (which == 0) ? Qo : (which == 1) ? Ko : Vo;
#pragma unroll
    for (int m = 0; m < 4; ++m) {
#pragma unroll
        for (int n = 0; n < 4; ++n) {
            int gc = offb + wc * 64 + n * 16 + fr;
#pragma unroll
            for (int j = 0; j < 4; ++j) {
                int gm = m0 + wr * 64 + m * 16 + fq * 4 + j;
                dst[(size_t)gm * dim + gc] = (_Float16)(acc[m][n][j] + biasv[n]);
            }
        }
    }
}

// ---------------------------------------------------------------------------
// MFMA flash attention: swapped-QK^T softmax; K direct from L2;
// defer-max THR=8; issue-early V double-buffer.
// ---------------------------------------------------------------------------
__global__ __launch_bounds__(256)
void attn_kernel(const _Float16* __restrict__ Q, const _Float16* __restrict__ K,
                 const _Float16* __restrict__ V, const int* __restrict__ cu,
                 float* __restrict__ out, int dim, int H, int B)
{
    const int w  = blockIdx.x;
    const int h  = w & (H - 1);
    const int wq = w / H;

    // heavy-first schedule: reversed-b flat scan (uniform scalar loop)
    int b = -1, qt = 0, acc = 0;
    for (int i = B - 1; i >= 0; --i) {
        int Li = cu[i + 1] - cu[i];
        int nq = (Li + 127) >> 7;
        if (wq >= acc && wq < acc + nq) { b = i; qt = wq - acc; }
        acc += nq;
    }
    if (b < 0) return;

    const int s0 = cu[b];
    const int L  = cu[b + 1] - s0;

    const int t    = threadIdx.x;
    const int wid  = t >> 6, lane = t & 63;
    const int fr   = lane & 15, fq = lane >> 4;

    __shared__ _Float16 Vt[64 * 72];      // 9 KB, [d][kv] padded
    __shared__ _Float16 Ps[4][32 * 72];   // 18 KB, per-wave P [q][kv] padded
    __shared__ float    Fs[4][32];        // per-wave fac / final l

    _Float16* Psw = &Ps[wid][0];
    float*    Fsw = &Fs[wid][0];

    // ---- Q fragments in registers; fold scale*log2(e) (exp2 softmax) ----
    const _Float16 qscale = (_Float16)(0.125f * 1.44269504f);
    half8 aq[2][2];
#pragma unroll
    for (int nt = 0; nt < 2; ++nt)
#pragma unroll
        for (int kc = 0; kc < 2; ++kc) {
            int qrow = qt * 128 + wid * 32 + nt * 16 + fr;
            int qr = (qrow < L) ? qrow : 0;
            half8 v = *(const half8*)(Q + (size_t)(s0 + qr) * dim + h * HD + kc * 32 + fq * 8);
#pragma unroll
            for (int i = 0; i < 8; ++i) v[i] = v[i] * qscale;
            aq[nt][kc] = v;
        }

    f32x4 o[2][4];
    float m2[2], l2[2];
#pragma unroll
    for (int qm = 0; qm < 2; ++qm)
#pragma unroll
        for (int n = 0; n < 4; ++n) o[qm][n] = (f32x4)0.f;
    m2[0] = m2[1] = -3.0e38f;
    l2[0] = l2[1] = 0.f;

    const int nkt = (L + 63) >> 6;
    const int vu = t & 31, vdc = t >> 5;   // V staging: kv pair 2u,2u+1; d = vdc*8..+8
    const _Float16* Kbase = K + (size_t)s0 * dim + h * HD;
    const _Float16* Vbase = V + (size_t)s0 * dim + h * HD + vdc * 8;

    // ---- prologue: issue V loads for tile 0 ----
    half8 va, vb;
    {
        int r0 = vu * 2, r1 = vu * 2 + 1;
        r0 = (r0 < L) ? r0 : L - 1;  r1 = (r1 < L) ? r1 : L - 1;
        va = *(const half8*)(Vbase + (size_t)r0 * dim);
        vb = *(const half8*)(Vbase + (size_t)r1 * dim);
    }

    for (int kt = 0; kt < nkt; ++kt) {
        __syncthreads();   // prev tile's Vt reads done (drains va/vb loads too)

        // ---- write Vt[d][kv] from prefetched regs, packed b32 ----
#pragma unroll
        for (int i = 0; i < 8; ++i) {
            union { _Float16 h[2]; unsigned u; } pk;
            pk.h[0] = va[i]; pk.h[1] = vb[i];
            *(unsigned*)&Vt[(vdc * 8 + i) * 72 + vu * 2] = pk.u;
        }
        __syncthreads();   // Vt visible

        // ---- S^T = mfma(K, Q/8'): K fragments direct from global (L2) ----
        f32x4 s2[4][2];
#pragma unroll
        for (int mt = 0; mt < 4; ++mt)
#pragma unroll
            for (int nt = 0; nt < 2; ++nt) s2[mt][nt] = (f32x4)0.f;

#pragma unroll
        for (int mt = 0; mt < 4; ++mt) {
            int krow = kt * 64 + mt * 16 + fr;
            int kr   = (krow < L) ? krow : L - 1;
            const _Float16* kp = Kbase + (size_t)kr * dim + fq * 8;
#pragma unroll
            for (int kc = 0; kc < 2; ++kc) {
                const half8 bk = *(const half8*)(kp + kc * 32);
                s2[mt][0] = __builtin_amdgcn_mfma_f32_16x16x32_f16(bk, aq[0][kc], s2[mt][0], 0, 0, 0);
                s2[mt][1] = __builtin_amdgcn_mfma_f32_16x16x32_f16(bk, aq[1][kc], s2[mt][1], 0, 0, 0);
            }
        }

        // ---- mask partial tile (kv = mt*16 + fq*4 + j) ----
        int ksz = L - kt * 64;
        if (ksz < 64) {
#pragma unroll
            for (int mt = 0; mt < 4; ++mt)
#pragma unroll
                for (int j = 0; j < 4; ++j)
                    if (mt * 16 + fq * 4 + j >= ksz) {
                        s2[mt][0][j] = -1.0e30f;
                        s2[mt][1][j] = -1.0e30f;
                    }
        }

        // ---- defer-max softmax: row max, wave-uniform rescale decision ----
        float mxv[2];
#pragma unroll
        for (int nt = 0; nt < 2; ++nt) {
            f32x4 mx4 = s2[0][nt];
#pragma unroll
            for (int mt = 1; mt < 4; ++mt)
#pragma unroll
                for (int j = 0; j < 4; ++j) mx4[j] = fmaxf(mx4[j], s2[mt][nt][j]);
            float mx = fmaxf(fmaxf(mx4[0], mx4[1]), fmaxf(mx4[2], mx4[3]));
            mx = fmaxf(mx, __shfl_xor(mx, 16));
            mx = fmaxf(mx, __shfl_xor(mx, 32));
            mxv[nt] = mx;
        }
        bool need = __any(mxv[0] > m2[0] + 8.f) || __any(mxv[1] > m2[1] + 8.f);
        if (need) {
#pragma unroll
            for (int nt = 0; nt < 2; ++nt) {
                float mnew = fmaxf(m2[nt], mxv[nt]);
                float facn = __builtin_exp2f(m2[nt] - mnew);
                m2[nt] = mnew;
                l2[nt] *= facn;
                if (fq == 0) Fsw[nt * 16 + fr] = facn;
            }
#pragma unroll
            for (int qm = 0; qm < 2; ++qm) {
                f32x4 fj = *(const f32x4*)&Fsw[qm * 16 + fq * 4];
#pragma unroll
                for (int n2 = 0; n2 < 4; ++n2)
#pragma unroll
                    for (int j = 0; j < 4; ++j) o[qm][n2][j] *= fj[j];
            }
        }

        // ---- exp pass + P writes (P bounded by 2^8 via defer-max) ----
#pragma unroll
        for (int nt = 0; nt < 2; ++nt) {
            f32x4 sum4 = (f32x4)0.f;
#pragma unroll
            for (int mt = 0; mt < 4; ++mt) {
                half4v ph;
#pragma unroll
                for (int j = 0; j < 4; ++j) {
                    float p = __builtin_exp2f(s2[mt][nt][j] - m2[nt]);
                    sum4[j] += p;
                    ph[j] = (_Float16)p;
                }
                *(half4v*)&Psw[(nt * 16 + fr) * 72 + mt * 16 + fq * 4] = ph;
            }
            float ls = (sum4[0] + sum4[1]) + (sum4[2] + sum4[3]);
            ls += __shfl_xor(ls, 16);
            ls += __shfl_xor(ls, 32);
            l2[nt] += ls;
        }

        // ---- issue-early: V loads for next tile (hide under PV) ----
        if (kt + 1 < nkt) {
            int r0 = (kt + 1) * 64 + vu * 2, r1 = r0 + 1;
            r0 = (r0 < L) ? r0 : L - 1;  r1 = (r1 < L) ? r1 : L - 1;
            va = *(const half8*)(Vbase + (size_t)r0 * dim);
            vb = *(const half8*)(Vbase + (size_t)r1 * dim);
        }

        // ---- O += P V : 16 MFMA per wave (Ps per-wave -> no barrier) ----
#pragma unroll
        for (int kc = 0; kc < 2; ++kc) {
            half8 ap0 = *(const half8*)&Psw[(0 * 16 + fr) * 72 + kc * 32 + fq * 8];
            half8 ap1 = *(const half8*)&Psw[(1 * 16 + fr) * 72 + kc * 32 + fq * 8];
#pragma unroll
            for (int n2 = 0; n2 < 4; ++n2) {
                half8 bv = *(const half8*)&Vt[(n2 * 16 + fr) * 72 + kc * 32 + fq * 8];
                o[0][n2] = __builtin_amdgcn_mfma_f32_16x16x32_f16(ap0, bv, o[0][n2], 0, 0, 0);
                o[1][n2] = __builtin_amdgcn_mfma_f32_16x16x32_f16(ap1, bv, o[1][n2], 0, 0, 0);
            }
        }
    }

    // ---- final l to o-row lanes via Fs, normalize + store ----
    if (fq == 0) { Fsw[fr] = l2[0]; Fsw[16 + fr] = l2[1]; }
#pragma unroll
    for (int qm = 0; qm < 2; ++qm) {
        f32x4 lj = *(const f32x4*)&Fsw[qm * 16 + fq * 4];
#pragma unroll
        for (int j = 0; j < 4; ++j) {
            int qrow = qt * 128 + wid * 32 + qm * 16 + fq * 4 + j;
            if (qrow >= L) continue;
            float inv = 1.0f / lj[j];
#pragma unroll
            for (int n2 = 0; n2 < 4; ++n2)
                out[(size_t)(s0 + qrow) * dim + h * HD + n2 * 16 + fr] = o[qm][n2][j] * inv;
        }
    }
}

// ---------------------------------------------------------------------------
extern "C" void kernel_launch(void* const* d_in, const int* in_sizes, int n_in,
                              void* d_out, int out_size, void* d_ws, size_t ws_size,
                              hipStream_t stream)
{
    const float* hs   = (const float*)d_in[0];
    const float* W    = (const float*)d_in[1];
    const float* bias = (const float*)d_in[2];
    const int*   cu   = (const int*)d_in[3];

    const int dim3x = in_sizes[2];        // 3072
    const int dim   = dim3x / 3;          // 1024
    const int nnz   = in_sizes[0] / dim;  // 8704
    const int B     = in_sizes[3] - 1;    // 16
    const int H     = dim / HD;           // 16
    const size_t nA = (size_t)nnz * dim;
    const size_t nW = (size_t)dim3x * dim;

    _Float16* Ah = (_Float16*)d_ws;
    _Float16* Wh = Ah + nA;
    _Float16* Qh = Wh + nW;
    _Float16* Kh = Qh + nA;
    _Float16* Vh = Kh + nA;

    cvt_kernel<<<1024, 256, 0, stream>>>(hs, W, Ah, Wh, (int)(nA / 4), (int)(nW / 4));

    dim3 g1(nnz / 128, dim3x / 128);
    qkv_gemm_kernel<<<g1, 256, 0, stream>>>(Ah, Wh, bias, Qh, Kh, Vh, dim, dim);

    const int maxWQ = nnz / 128 + B;      // upper bound on total q-tiles
    attn_kernel<<<maxWQ * H, 256, 0, stream>>>(Qh, Kh, Vh, cu, (float*)d_out, dim, H, B);
}

// Round 11
// 238.936 us; speedup vs baseline: 1.1017x; 1.1017x over previous
//
#include <hip/hip_runtime.h>
#include <math.h>

// BertFlashSelfAttention (varlen, H=16, D=64)
// Phase 0: fp32 -> f16 convert (hidden, Wqkv)
// Phase 1: QKV GEMM, BK=64, XOR-swizzled LDS (validated r9)
// Phase 2: MFMA flash attention: swapped-QK^T softmax + K LDS staging
//          (validated r9) + defer-max THR=8 + issue-early V regs (r10 parts).

#define HD 64

typedef _Float16 half8 __attribute__((ext_vector_type(8)));
typedef _Float16 half4v __attribute__((ext_vector_type(4)));
typedef float f32x4 __attribute__((ext_vector_type(4)));

#define GLP(p) ((__attribute__((address_space(1))) void*)(p))
#define LDSP(p) ((__attribute__((address_space(3))) void*)(p))

// ---------------------------------------------------------------------------
// fp32 -> f16 conversion (grid-stride, float4 in / half4 out)
// ---------------------------------------------------------------------------
__global__ __launch_bounds__(256)
void cvt_kernel(const float* __restrict__ A, const float* __restrict__ W,
                _Float16* __restrict__ Ah, _Float16* __restrict__ Wh,
                int nA4, int nW4)
{
    int total = nA4 + nW4;
    for (int i = blockIdx.x * blockDim.x + threadIdx.x; i < total;
         i += gridDim.x * blockDim.x) {
        const float* src; _Float16* dst; int j;
        if (i < nA4) { src = A; dst = Ah; j = i; }
        else         { src = W; dst = Wh; j = i - nA4; }
        float4 v = *(const float4*)(src + (size_t)j * 4);
        half4v h;
        h.x = (_Float16)v.x; h.y = (_Float16)v.y;
        h.z = (_Float16)v.z; h.w = (_Float16)v.w;
        *(half4v*)(dst + (size_t)j * 4) = h;
    }
}

// ---------------------------------------------------------------------------
// QKV GEMM (unchanged, validated r9): BK=64, XOR-swizzled LDS, f16 MFMA.
// ---------------------------------------------------------------------------
__global__ __launch_bounds__(256)
void qkv_gemm_kernel(const _Float16* __restrict__ Ah, const _Float16* __restrict__ Wh,
                     const float* __restrict__ bias,
                     _Float16* __restrict__ Qo, _Float16* __restrict__ Ko,
                     _Float16* __restrict__ Vo,
                     int Kd, int dim)
{
    const int bm = blockIdx.x, bn = blockIdx.y;
    const int t = threadIdx.x;
    const int wid = t >> 6, lane = t & 63;
    const int wr = wid >> 1, wc = wid & 1;
    const int fr = lane & 15, fq = lane >> 4;

    __shared__ _Float16 As[128 * 64];   // 16 KB, swizzled 128B rows
    __shared__ _Float16 Bs[128 * 64];

    const int m0 = bm * 128, n0 = bn * 128;

    f32x4 acc[4][4];
#pragma unroll
    for (int m = 0; m < 4; ++m)
#pragma unroll
        for (int n = 0; n < 4; ++n) acc[m][n] = (f32x4)0.f;

    float biasv[4];
#pragma unroll
    for (int n = 0; n < 4; ++n)
        biasv[n] = bias[n0 + wc * 64 + n * 16 + fr];

    int srow[4], slb[4];
#pragma unroll
    for (int i = 0; i < 4; ++i) {
        int c = t + 256 * i;
        srow[i] = c >> 3;
        slb[i]  = ((c & 7) << 4) ^ ((srow[i] & 7) << 4);
    }

    for (int k0 = 0; k0 < Kd; k0 += 64) {
        __syncthreads();
        {
            const char* Ab = (const char*)Ah + ((size_t)m0 * Kd + k0) * 2;
            const char* Bb = (const char*)Wh + ((size_t)n0 * Kd + k0) * 2;
#pragma unroll
            for (int i = 0; i < 4; ++i) {
                int phys = (t + 256 * i) * 16;
                __builtin_amdgcn_global_load_lds(GLP(Ab + (size_t)srow[i] * Kd * 2 + slb[i]),
                                                 LDSP((char*)As + phys), 16, 0, 0);
                __builtin_amdgcn_global_load_lds(GLP(Bb + (size_t)srow[i] * Kd * 2 + slb[i]),
                                                 LDSP((char*)Bs + phys), 16, 0, 0);
            }
        }
        __syncthreads();

#pragma unroll
        for (int kc = 0; kc < 2; ++kc) {
            half8 a[4], b[4];
#pragma unroll
            for (int m = 0; m < 4; ++m) {
                int row = wr * 64 + m * 16 + fr;
                a[m] = *(const half8*)((const char*)As + row * 128 +
                        ((kc * 64 + fq * 16) ^ ((fr & 7) << 4)));
            }
#pragma unroll
            for (int n = 0; n < 4; ++n) {
                int row = wc * 64 + n * 16 + fr;
                b[n] = *(const half8*)((const char*)Bs + row * 128 +
                        ((kc * 64 + fq * 16) ^ ((fr & 7) << 4)));
            }
#pragma unroll
            for (int m = 0; m < 4; ++m)
#pragma unroll
                for (int n = 0; n < 4; ++n)
                    acc[m][n] = __builtin_amdgcn_mfma_f32_16x16x32_f16(a[m], b[n], acc[m][n], 0, 0, 0);
        }
    }

    const int which = n0 / dim;
    const int offb  = n0 - which * dim;
    _Float16* dst = (which == 0) ? Qo : (which == 1) ? Ko : Vo;
#pragma unroll
    for (int m = 0; m < 4; ++m) {
#pragma unroll
        for (int n = 0; n < 4; ++n) {
            int gc = offb + wc * 64 + n * 16 + fr;
#pragma unroll
            for (int j = 0; j < 4; ++j) {
                int gm = m0 + wr * 64 + m * 16 + fq * 4 + j;
                dst[(size_t)gm * dim + gc] = (_Float16)(acc[m][n][j] + biasv[n]);
            }
        }
    }
}

// ---------------------------------------------------------------------------
// MFMA flash attention: swapped-QK^T softmax; K staged via global_load_lds
// with XOR-swizzled source (r9); defer-max THR=8; issue-early V regs.
// ---------------------------------------------------------------------------
__global__ __launch_bounds__(256)
void attn_kernel(const _Float16* __restrict__ Q, const _Float16* __restrict__ K,
                 const _Float16* __restrict__ V, const int* __restrict__ cu,
                 float* __restrict__ out, int dim, int H, int B)
{
    const int w  = blockIdx.x;
    const int h  = w & (H - 1);
    const int wq = w / H;

    // heavy-first schedule: reversed-b flat scan (uniform scalar loop)
    int b = -1, qt = 0, acc = 0;
    for (int i = B - 1; i >= 0; --i) {
        int Li = cu[i + 1] - cu[i];
        int nq = (Li + 127) >> 7;
        if (wq >= acc && wq < acc + nq) { b = i; qt = wq - acc; }
        acc += nq;
    }
    if (b < 0) return;

    const int s0 = cu[b];
    const int L  = cu[b + 1] - s0;

    const int t    = threadIdx.x;
    const int wid  = t >> 6, lane = t & 63;
    const int fr   = lane & 15, fq = lane >> 4;

    __shared__ _Float16 Ks[64 * 64];      // 8 KB, swizzled 128B rows
    __shared__ _Float16 Vt[64 * 72];      // 9 KB, [d][kv] padded
    __shared__ _Float16 Ps[4][32 * 72];   // 18 KB, per-wave P [q][kv] padded
    __shared__ float    Fs[4][32];        // per-wave fac / final l

    _Float16* Psw = &Ps[wid][0];
    float*    Fsw = &Fs[wid][0];

    // ---- Q fragments in registers; fold scale*log2(e) (exp2 softmax) ----
    const _Float16 qscale = (_Float16)(0.125f * 1.44269504f);
    half8 aq[2][2];
#pragma unroll
    for (int nt = 0; nt < 2; ++nt)
#pragma unroll
        for (int kc = 0; kc < 2; ++kc) {
            int qrow = qt * 128 + wid * 32 + nt * 16 + fr;
            int qr = (qrow < L) ? qrow : 0;
            half8 v = *(const half8*)(Q + (size_t)(s0 + qr) * dim + h * HD + kc * 32 + fq * 8);
#pragma unroll
            for (int i = 0; i < 8; ++i) v[i] = v[i] * qscale;
            aq[nt][kc] = v;
        }

    f32x4 o[2][4];
    float m2[2], l2[2];
#pragma unroll
    for (int qm = 0; qm < 2; ++qm)
#pragma unroll
        for (int n = 0; n < 4; ++n) o[qm][n] = (f32x4)0.f;
    m2[0] = m2[1] = -3.0e38f;
    l2[0] = l2[1] = 0.f;

    const int nkt = (L + 63) >> 6;
    const int vu = t & 31, vdc = t >> 5;   // V staging: kv pair 2u,2u+1; d = vdc*8..+8
    const _Float16* Vbase = V + (size_t)s0 * dim + h * HD + vdc * 8;

    // ---- prologue: V loads for tile 0 into regs ----
    half8 va, vb;
    {
        int r0 = vu * 2, r1 = vu * 2 + 1;
        r0 = (r0 < L) ? r0 : L - 1;  r1 = (r1 < L) ? r1 : L - 1;
        va = *(const half8*)(Vbase + (size_t)r0 * dim);
        vb = *(const half8*)(Vbase + (size_t)r1 * dim);
    }

    for (int kt = 0; kt < nkt; ++kt) {
        __syncthreads();   // prev tile's Ks/Vt reads done; va/vb loads drained

        // ---- stage K: linear LDS dest, XOR-swizzled global source ----
#pragma unroll
        for (int cc = 0; cc < 2; ++cc) {
            int c    = wid * 2 + cc;            // chunk 0..7 (1 KB each)
            int phys = c * 1024 + lane * 16;    // linear LDS byte
            int r    = phys >> 7;               // kv row (128B rows)
            int lb   = (phys & 127) ^ ((r & 7) << 4);
            int krow = kt * 64 + r;
            int kr   = (krow < L) ? krow : 0;
            const char* src = (const char*)K + ((size_t)(s0 + kr) * dim + h * HD) * 2 + lb;
            __builtin_amdgcn_global_load_lds(GLP(src), LDSP((char*)Ks + phys), 16, 0, 0);
        }
        // ---- write Vt[d][kv] from prefetched regs, packed b32 ----
#pragma unroll
        for (int i = 0; i < 8; ++i) {
            union { _Float16 h[2]; unsigned u; } pk;
            pk.h[0] = va[i]; pk.h[1] = vb[i];
            *(unsigned*)&Vt[(vdc * 8 + i) * 72 + vu * 2] = pk.u;
        }
        __syncthreads();   // staged data visible

        // ---- S^T = mfma(K, Q/8'): 16 MFMA per wave ----
        f32x4 s2[4][2];
#pragma unroll
        for (int mt = 0; mt < 4; ++mt)
#pragma unroll
            for (int nt = 0; nt < 2; ++nt) s2[mt][nt] = (f32x4)0.f;

#pragma unroll
        for (int mt = 0; mt < 4; ++mt)
#pragma unroll
            for (int kc = 0; kc < 2; ++kc) {
                const half8 bk = *(const half8*)((const char*)Ks +
                    ((mt * 16 + fr) << 7) + (((kc << 6) + (fq << 4)) ^ ((fr & 7) << 4)));
                s2[mt][0] = __builtin_amdgcn_mfma_f32_16x16x32_f16(bk, aq[0][kc], s2[mt][0], 0, 0, 0);
                s2[mt][1] = __builtin_amdgcn_mfma_f32_16x16x32_f16(bk, aq[1][kc], s2[mt][1], 0, 0, 0);
            }

        // ---- mask partial tile (kv = mt*16 + fq*4 + j) ----
        int ksz = L - kt * 64;
        if (ksz < 64) {
#pragma unroll
            for (int mt = 0; mt < 4; ++mt)
#pragma unroll
                for (int j = 0; j < 4; ++j)
                    if (mt * 16 + fq * 4 + j >= ksz) {
                        s2[mt][0][j] = -1.0e30f;
                        s2[mt][1][j] = -1.0e30f;
                    }
        }

        // ---- defer-max softmax: row max, wave-uniform rescale decision ----
        float mxv[2];
#pragma unroll
        for (int nt = 0; nt < 2; ++nt) {
            f32x4 mx4 = s2[0][nt];
#pragma unroll
            for (int mt = 1; mt < 4; ++mt)
#pragma unroll
                for (int j = 0; j < 4; ++j) mx4[j] = fmaxf(mx4[j], s2[mt][nt][j]);
            float mx = fmaxf(fmaxf(mx4[0], mx4[1]), fmaxf(mx4[2], mx4[3]));
            mx = fmaxf(mx, __shfl_xor(mx, 16));
            mx = fmaxf(mx, __shfl_xor(mx, 32));
            mxv[nt] = mx;
        }
        bool need = __any(mxv[0] > m2[0] + 8.f) || __any(mxv[1] > m2[1] + 8.f);
        if (need) {
#pragma unroll
            for (int nt = 0; nt < 2; ++nt) {
                float mnew = fmaxf(m2[nt], mxv[nt]);
                float facn = __builtin_exp2f(m2[nt] - mnew);
                m2[nt] = mnew;
                l2[nt] *= facn;
                if (fq == 0) Fsw[nt * 16 + fr] = facn;
            }
#pragma unroll
            for (int qm = 0; qm < 2; ++qm) {
                f32x4 fj = *(const f32x4*)&Fsw[qm * 16 + fq * 4];
#pragma unroll
                for (int n2 = 0; n2 < 4; ++n2)
#pragma unroll
                    for (int j = 0; j < 4; ++j) o[qm][n2][j] *= fj[j];
            }
        }

        // ---- exp pass + P writes (P bounded by 2^8 via defer-max) ----
#pragma unroll
        for (int nt = 0; nt < 2; ++nt) {
            f32x4 sum4 = (f32x4)0.f;
#pragma unroll
            for (int mt = 0; mt < 4; ++mt) {
                half4v ph;
#pragma unroll
                for (int j = 0; j < 4; ++j) {
                    float p = __builtin_exp2f(s2[mt][nt][j] - m2[nt]);
                    sum4[j] += p;
                    ph[j] = (_Float16)p;
                }
                *(half4v*)&Psw[(nt * 16 + fr) * 72 + mt * 16 + fq * 4] = ph;
            }
            float ls = (sum4[0] + sum4[1]) + (sum4[2] + sum4[3]);
            ls += __shfl_xor(ls, 16);
            ls += __shfl_xor(ls, 32);
            l2[nt] += ls;
        }

        // ---- issue-early: V loads for next tile (hide under PV) ----
        if (kt + 1 < nkt) {
            int r0 = (kt + 1) * 64 + vu * 2, r1 = r0 + 1;
            r0 = (r0 < L) ? r0 : L - 1;  r1 = (r1 < L) ? r1 : L - 1;
            va = *(const half8*)(Vbase + (size_t)r0 * dim);
            vb = *(const half8*)(Vbase + (size_t)r1 * dim);
        }

        // ---- O += P V : 16 MFMA per wave (Ps per-wave -> no barrier) ----
#pragma unroll
        for (int kc = 0; kc < 2; ++kc) {
            half8 ap0 = *(const half8*)&Psw[(0 * 16 + fr) * 72 + kc * 32 + fq * 8];
            half8 ap1 = *(const half8*)&Psw[(1 * 16 + fr) * 72 + kc * 32 + fq * 8];
#pragma unroll
            for (int n2 = 0; n2 < 4; ++n2) {
                half8 bv = *(const half8*)&Vt[(n2 * 16 + fr) * 72 + kc * 32 + fq * 8];
                o[0][n2] = __builtin_amdgcn_mfma_f32_16x16x32_f16(ap0, bv, o[0][n2], 0, 0, 0);
                o[1][n2] = __builtin_amdgcn_mfma_f32_16x16x32_f16(ap1, bv, o[1][n2], 0, 0, 0);
            }
        }
    }

    // ---- final l to o-row lanes via Fs, normalize + store ----
    if (fq == 0) { Fsw[fr] = l2[0]; Fsw[16 + fr] = l2[1]; }
#pragma unroll
    for (int qm = 0; qm < 2; ++qm) {
        f32x4 lj = *(const f32x4*)&Fsw[qm * 16 + fq * 4];
#pragma unroll
        for (int j = 0; j < 4; ++j) {
            int qrow = qt * 128 + wid * 32 + qm * 16 + fq * 4 + j;
            if (qrow >= L) continue;
            float inv = 1.0f / lj[j];
#pragma unroll
            for (int n2 = 0; n2 < 4; ++n2)
                out[(size_t)(s0 + qrow) * dim + h * HD + n2 * 16 + fr] = o[qm][n2][j] * inv;
        }
    }
}

// ---------------------------------------------------------------------------
extern "C" void kernel_launch(void* const* d_in, const int* in_sizes, int n_in,
                              void* d_out, int out_size, void* d_ws, size_t ws_size,
                              hipStream_t stream)
{
    const float* hs   = (const float*)d_in[0];
    const float* W    = (const float*)d_in[1];
    const float* bias = (const float*)d_in[2];
    const int*   cu   = (const int*)d_in[3];

    const int dim3x = in_sizes[2];        // 3072
    const int dim   = dim3x / 3;          // 1024
    const int nnz   = in_sizes[0] / dim;  // 8704
    const int B     = in_sizes[3] - 1;    // 16
    const int H     = dim / HD;           // 16
    const size_t nA = (size_t)nnz * dim;
    const size_t nW = (size_t)dim3x * dim;

    _Float16* Ah = (_Float16*)d_ws;
    _Float16* Wh = Ah + nA;
    _Float16* Qh = Wh + nW;
    _Float16* Kh = Qh + nA;
    _Float16* Vh = Kh + nA;

    cvt_kernel<<<1024, 256, 0, stream>>>(hs, W, Ah, Wh, (int)(nA / 4), (int)(nW / 4));

    dim3 g1(nnz / 128, dim3x / 128);
    qkv_gemm_kernel<<<g1, 256, 0, stream>>>(Ah, Wh, bias, Qh, Kh, Vh, dim, dim);

    const int maxWQ = nnz / 128 + B;      // upper bound on total q-tiles
    attn_kernel<<<maxWQ * H, 256, 0, stream>>>(Qh, Kh, Vh, cu, (float*)d_out, dim, H, B);
}